// Round 2
// baseline (16852.510 us; speedup 1.0000x reference)
//
#include <hip/hip_runtime.h>
#include <cstdint>
#include <cstddef>

typedef _Float16 half2_t __attribute__((ext_vector_type(2)));
typedef _Float16 half4_t __attribute__((ext_vector_type(4)));
typedef _Float16 half8_t __attribute__((ext_vector_type(8)));
typedef float    float4_t __attribute__((ext_vector_type(4)));

#define NB 32
#define NR 196
#define DE 512
#define DD 512
#define NV 32000
#define NT 64
#define NG 2048
#define CAPLEN 65
#define NWG 256

#if defined(__has_builtin)
#if __has_builtin(__builtin_amdgcn_fdot2)
#define HAS_FDOT2 1
#endif
#endif

__device__ __forceinline__ float fdot2f(half2_t a, half2_t b, float c) {
#ifdef HAS_FDOT2
  return __builtin_amdgcn_fdot2(a, b, c, false);
#else
  return c + (float)a[0]*(float)b[0] + (float)a[1]*(float)b[1];
#endif
}

__device__ __forceinline__ float fast_tanh(float x) {
  float e = __expf(2.f*x);
  return 1.f - 2.f/(e + 1.f);
}
__device__ __forceinline__ float fast_sig(float x) {
  return 1.f/(1.f + __expf(-x));
}

union U32H2 { unsigned u; half2_t h; };

__device__ __forceinline__ unsigned ld_au(const unsigned* p) {
  return __hip_atomic_load(p, __ATOMIC_RELAXED, __HIP_MEMORY_SCOPE_AGENT);
}
__device__ __forceinline__ float ld_af(const float* p) {
  return __hip_atomic_load(p, __ATOMIC_RELAXED, __HIP_MEMORY_SCOPE_AGENT);
}
__device__ __forceinline__ void st_au(unsigned* p, unsigned v) {
  __hip_atomic_store(p, v, __ATOMIC_RELAXED, __HIP_MEMORY_SCOPE_AGENT);
}
__device__ __forceinline__ void st_af(float* p, float v) {
  __hip_atomic_store(p, v, __ATOMIC_RELAXED, __HIP_MEMORY_SCOPE_AGENT);
}

// Two-level grid barrier: 8 group counters (32 arrivals each) -> master(8) -> epoch.
// bar layout (unsigned words): group g counter at g*64, master at 512, epoch at 576.
__device__ __forceinline__ void gbar(unsigned* bar, int g, unsigned target) {
  __threadfence();
  __syncthreads();
  if (threadIdx.x == 0) {
    unsigned* cnt    = bar + (g & 7)*64;
    unsigned* master = bar + 512;
    unsigned* epoch  = bar + 576;
    unsigned p = __hip_atomic_fetch_add(cnt, 1u, __ATOMIC_ACQ_REL, __HIP_MEMORY_SCOPE_AGENT);
    if (p == 31u) {
      __hip_atomic_store(cnt, 0u, __ATOMIC_RELAXED, __HIP_MEMORY_SCOPE_AGENT);
      unsigned q = __hip_atomic_fetch_add(master, 1u, __ATOMIC_ACQ_REL, __HIP_MEMORY_SCOPE_AGENT);
      if (q == 7u) {
        __hip_atomic_store(master, 0u, __ATOMIC_RELAXED, __HIP_MEMORY_SCOPE_AGENT);
        __hip_atomic_store(epoch, target, __ATOMIC_RELEASE, __HIP_MEMORY_SCOPE_AGENT);
      }
    }
    while (__hip_atomic_load(epoch, __ATOMIC_ACQUIRE, __HIP_MEMORY_SCOPE_AGENT) != target) {
      __builtin_amdgcn_s_sleep(2);
    }
  }
  __syncthreads();
  __threadfence();
}

// ======================= prep: fused cvt/gather/bias/init/zero =======================
// task offsets (workgroups of 256 threads)
#define O_Z    0
#define N_Z    1027
#define O_WFC  (O_Z + N_Z)         // 16000
#define O_WENC (O_WFC + 16000)     // 256
#define O_WDEC (O_WENC + 256)      // 256
#define O_WIH  (O_WDEC + 256)      // 2048
#define O_WHH  (O_WIH + 2048)      // 1024
#define O_IMGF (O_WHH + 1024)      // 3136
#define O_GATH (O_IMGF + 3136)     // 2048
#define O_BIAS (O_GATH + 2048)     // 1
#define O_INIT (O_BIAS + 1)        // 256
#define N_PREP (O_INIT + 256)
#define ZERO_F4 262816             // (2560 + 8192 + 4194304) / 16

__device__ __forceinline__ void cvt_blk(const float* s, _Float16* d, int base) {
  float4 v = *(const float4*)(s + base);
  half4_t h;
  h[0] = (_Float16)v.x; h[1] = (_Float16)v.y; h[2] = (_Float16)v.z; h[3] = (_Float16)v.w;
  *(half4_t*)(d + base) = h;
}

__global__ void __launch_bounds__(256) prep_k(
    const float* __restrict__ imgf, const int* __restrict__ cap, const float* __restrict__ emb,
    const float* __restrict__ Wh0, const float* __restrict__ bh0,
    const float* __restrict__ Wc0, const float* __restrict__ bc0,
    const float* __restrict__ Wenc, const float* __restrict__ Wdec,
    const float* __restrict__ W_ih, const float* __restrict__ b_ih,
    const float* __restrict__ W_hh, const float* __restrict__ b_hh,
    const float* __restrict__ Wfc,
    _Float16* __restrict__ Wenc_h, _Float16* __restrict__ Wdec_h,
    _Float16* __restrict__ Wih_h, _Float16* __restrict__ Whh_h,
    _Float16* __restrict__ Wfc_h, _Float16* __restrict__ imgf_h,
    _Float16* __restrict__ X_h, float* __restrict__ bsum,
    float* __restrict__ c0g, unsigned* __restrict__ h_glob,
    float4_t* __restrict__ zbase) {
  __shared__ float fm[512];
  __shared__ float hp[64];
  __shared__ float cpp[64];
  int bid = blockIdx.x, tid = threadIdx.x;
  if (bid < O_WFC) {
    int idx = (bid - O_Z)*256 + tid;
    if (idx < ZERO_F4) zbase[idx] = (float4_t){0.f, 0.f, 0.f, 0.f};
  } else if (bid < O_WENC) {
    cvt_blk(Wfc, Wfc_h, (bid - O_WFC)*1024 + tid*4);
  } else if (bid < O_WDEC) {
    cvt_blk(Wenc, Wenc_h, (bid - O_WENC)*1024 + tid*4);
  } else if (bid < O_WIH) {
    cvt_blk(Wdec, Wdec_h, (bid - O_WDEC)*1024 + tid*4);
  } else if (bid < O_WHH) {
    cvt_blk(W_ih, Wih_h, (bid - O_WIH)*1024 + tid*4);
  } else if (bid < O_IMGF) {
    cvt_blk(W_hh, Whh_h, (bid - O_WHH)*1024 + tid*4);
  } else if (bid < O_GATH) {
    cvt_blk(imgf, imgf_h, (bid - O_IMGF)*1024 + tid*4);
  } else if (bid < O_BIAS) {
    int r = bid - O_GATH;           // r = t*32 + b
    int t = r >> 5, b = r & 31;
    int tok = cap[b*CAPLEN + t];
    const float* s = emb + (size_t)tok*DE;
    _Float16* d = X_h + (size_t)r*DE;
    d[tid] = (_Float16)s[tid];
    d[tid + 256] = (_Float16)s[tid + 256];
  } else if (bid < O_INIT) {
    for (int i = tid; i < NG; i += 256) bsum[i] = b_ih[i] + b_hh[i];
  } else {
    int id2 = bid - O_INIT;
    int b = id2 >> 3, dg = id2 & 7;
    // feat mean
    for (int dI = tid; dI < DE; dI += 256) {
      float s = 0.f;
      const float* p = imgf + ((size_t)b*NR)*DE + dI;
      for (int n = 0; n < NR; n++) s += p[(size_t)n*DE];
      fm[dI] = s * (1.f/196.f);
    }
    __syncthreads();
    int dloc = tid >> 2, kq = tid & 3;
    int d = dg*64 + dloc;
    const float* whr = Wh0 + (size_t)d*DE + kq*128;
    const float* wcr = Wc0 + (size_t)d*DE + kq*128;
    const float* fmk = fm + kq*128;
    float ha = 0.f, ca = 0.f;
    for (int k = 0; k < 128; k++) { ha += fmk[k]*whr[k]; ca += fmk[k]*wcr[k]; }
    ha += __shfl_down(ha, 2); ha += __shfl_down(ha, 1);
    ca += __shfl_down(ca, 2); ca += __shfl_down(ca, 1);
    if (kq == 0) { hp[dloc] = ha + bh0[d]; cpp[dloc] = ca + bc0[d]; }
    __syncthreads();
    if (tid < 64) c0g[b*DD + dg*64 + tid] = cpp[tid];
    if (tid < 32) {
      U32H2 p;
      p.h[0] = (_Float16)hp[tid*2];
      p.h[1] = (_Float16)hp[tid*2 + 1];
      h_glob[b*256 + dg*32 + tid] = p.u;
    }
  }
}

// ======================= shared MFMA GEMM tile (64x64 per wave) =======================
template<int MODE>
__device__ __forceinline__ void gemm_tile(const _Float16* __restrict__ A, int lda,
    const _Float16* __restrict__ B, int ldb, void* __restrict__ Cp, int ldc,
    const float* __restrict__ bias, int K, int bx, int by) {
  int wave = threadIdx.x >> 6, lane = threadIdx.x & 63;
  int m0 = by*128 + (wave >> 1)*64;
  int n0 = bx*128 + (wave & 1)*64;
  int lr = lane & 15, quad = lane >> 4;
  float4_t acc[4][4];
  #pragma unroll
  for (int i = 0; i < 4; i++)
    #pragma unroll
    for (int j = 0; j < 4; j++)
      acc[i][j] = (float4_t){0.f, 0.f, 0.f, 0.f};
  const _Float16* Ap = A + (size_t)(m0 + lr)*lda + quad*8;
  const _Float16* Bp = B + (size_t)(n0 + lr)*ldb + quad*8;
  for (int k0 = 0; k0 < K; k0 += 32) {
    half8_t af[4], bf[4];
    #pragma unroll
    for (int i = 0; i < 4; i++) af[i] = *(const half8_t*)(Ap + (size_t)i*16*lda + k0);
    #pragma unroll
    for (int i = 0; i < 4; i++) bf[i] = *(const half8_t*)(Bp + (size_t)i*16*ldb + k0);
    #pragma unroll
    for (int mi = 0; mi < 4; mi++)
      #pragma unroll
      for (int ni = 0; ni < 4; ni++)
        acc[mi][ni] = __builtin_amdgcn_mfma_f32_16x16x32_f16(af[mi], bf[ni], acc[mi][ni], 0, 0, 0);
  }
  #pragma unroll
  for (int mi = 0; mi < 4; mi++) {
    #pragma unroll
    for (int ni = 0; ni < 4; ni++) {
      int col = n0 + ni*16 + lr;
      float bv = (MODE == 1) ? 0.f : bias[col];
      #pragma unroll
      for (int r = 0; r < 4; r++) {
        int row = m0 + mi*16 + quad*4 + r;
        if (MODE == 1) {
          ((_Float16*)Cp)[(size_t)row*ldc + col] = (_Float16)acc[mi][ni][r];
        } else if (MODE == 0) {
          ((float*)Cp)[(size_t)row*ldc + col] = acc[mi][ni][r] + bv;
        } else {
          size_t orow = (size_t)((row & 31)*NT + (row >> 5));
          ((float*)Cp)[orow*ldc + col] = acc[mi][ni][r] + bv;
        }
      }
    }
  }
}

// ======================= prologue GEMMs (fproj + Xg) fused =======================
__global__ void __launch_bounds__(256) g2_k(const _Float16* __restrict__ imgf_h,
    const _Float16* __restrict__ Wenc_h, _Float16* __restrict__ fproj_h,
    const _Float16* __restrict__ X_h, const _Float16* __restrict__ Wih_h,
    float* __restrict__ Xg, const float* __restrict__ bsum) {
  int id = blockIdx.x;
  if (id < 196) {
    gemm_tile<1>(imgf_h, 512, Wenc_h, 512, fproj_h, 512, nullptr, 512, id & 3, id >> 2);
  } else {
    int i2 = id - 196;
    gemm_tile<0>(X_h, 512, Wih_h, 1024, Xg, 2048, bsum, 512, i2 & 15, i2 >> 4);
  }
}

// ======================= persistent recurrence kernel =======================
__global__ void __launch_bounds__(512) rec_k(
    const _Float16* __restrict__ Wdec_h, const _Float16* __restrict__ Wih_h,
    const _Float16* __restrict__ Whh_h, const _Float16* __restrict__ fproj_h,
    const _Float16* __restrict__ imgf_h, const float* __restrict__ v_att,
    const float* __restrict__ Xg, const float* __restrict__ c0g,
    unsigned* __restrict__ h_glob, float* __restrict__ hW_glob,
    float* __restrict__ ctx_acc, float* __restrict__ S_buf,
    float* __restrict__ alpha_raw, unsigned* __restrict__ Hu,
    unsigned* __restrict__ bar) {
  __shared__ _Float16 wdec_l[2*512];
  __shared__ _Float16 wctx_l[8*520];
  __shared__ _Float16 whh_l[8*520];
  __shared__ _Float16 h_l[16*520];
  __shared__ _Float16 ctx_l[16*520];
  __shared__ float vl_l[512];
  __shared__ float hW_l[512];
  __shared__ float acc_h_l[256];
  __shared__ float gl[256];
  __shared__ float epart[16*33];
  __shared__ float expv_l[32];
  __shared__ float S_l[32];

  int g = blockIdx.x, tid = threadIdx.x;
  int d0 = g*2;

  // ---- one-time staging: gate weight rows, Wdec rows, v_att ----
  for (int idx = tid; idx < 8*64; idx += 512) {
    int r = idx >> 6, c8 = (idx & 63)*8;
    int typ = r >> 1, dl = r & 1;
    size_t i_row = (size_t)(typ*DD + d0 + dl);
    *(half8_t*)(wctx_l + r*520 + c8) = *(const half8_t*)(Wih_h + i_row*1024 + 512 + c8);
    *(half8_t*)(whh_l + r*520 + c8)  = *(const half8_t*)(Whh_h + i_row*DD + c8);
  }
  for (int idx = tid; idx < 2*64; idx += 512) {
    int r = idx >> 6, c8 = (idx & 63)*8;
    *(half8_t*)(wdec_l + r*512 + c8) = *(const half8_t*)(Wdec_h + (size_t)(d0 + r)*DD + c8);
  }
  if (tid < 512) vl_l[tid] = v_att[tid];
  float c_reg = 0.f;
  if (tid < 64) c_reg = c0g[(tid >> 1)*DD + d0 + (tid & 1)];
  __syncthreads();

  int ab = g >> 3, aq = g & 7;
  int an0 = (aq*196) >> 3;
  int ansz = (((aq + 1)*196) >> 3) - an0;
  unsigned bc = 0;

  #pragma unroll 1
  for (int t = 0; t < NT; t++) {
    // ================= P0: stage h, hW d-slice, Whh·h gate partials =================
    #pragma unroll 1
    for (int half = 0; half < 2; half++) {
      int bo = half*16;
      for (int i = tid; i < 4096; i += 512) {
        int bl = i >> 8, k2 = i & 255;
        U32H2 x; x.u = ld_au(&h_glob[(bo + bl)*256 + k2]);
        *(half2_t*)(h_l + bl*520 + k2*2) = x.h;
      }
      __syncthreads();
      {
        int bl = tid >> 5, dl = (tid >> 4) & 1, kq = tid & 15;
        const half2_t* wd = (const half2_t*)(wdec_l + dl*512);
        const half2_t* hh = (const half2_t*)(h_l + bl*520);
        float a = 0.f;
        #pragma unroll
        for (int i = 0; i < 16; i++) {
          int k2 = kq + i*16;
          a = fdot2f(wd[k2], hh[k2], a);
        }
        a += __shfl_down(a, 8); a += __shfl_down(a, 4);
        a += __shfl_down(a, 2); a += __shfl_down(a, 1);
        if (kq == 0) st_af(&hW_glob[(bo + bl)*DD + d0 + dl], a);
      }
      {
        int bl = tid >> 5, rr = (tid >> 2) & 7, kh = tid & 3;
        const half2_t* wr = (const half2_t*)(whh_l + rr*520);
        const half2_t* hh = (const half2_t*)(h_l + bl*520);
        float a = 0.f;
        #pragma unroll 8
        for (int i = 0; i < 64; i++) {
          int k2 = kh + 4*i;
          a = fdot2f(wr[k2], hh[k2], a);
        }
        a += __shfl_down(a, 2); a += __shfl_down(a, 1);
        if (kh == 0) acc_h_l[(bo + bl)*8 + rr] = a;
      }
      __syncthreads();
    }
    gbar(bar, g, ++bc);
    // ================= P1: attention (all 256 wgs; 8 per batch elem) =================
    {
      if (tid < 512) hW_l[tid] = ld_af(&hW_glob[ab*DD + tid]);
      __syncthreads();
      {
        int dq = tid >> 5, nl = tid & 31;
        float acc = 0.f;
        if (nl < ansz) {
          const half8_t* fp = (const half8_t*)(fproj_h + ((size_t)(ab*NR + an0 + nl))*DD) + dq;
          #pragma unroll
          for (int i = 0; i < 4; i++) {
            half8_t f8 = fp[i*16];
            #pragma unroll
            for (int j = 0; j < 8; j++) {
              int dI = i*128 + dq*8 + j;
              acc += vl_l[dI] * fast_tanh((float)f8[j] + hW_l[dI]);
            }
          }
        }
        epart[dq*33 + nl] = acc;
      }
      __syncthreads();
      if (tid < 32) {
        float e = 0.f;
        #pragma unroll
        for (int dq = 0; dq < 16; dq++) e += epart[dq*33 + tid];
        float ex = (tid < ansz) ? __expf(e - 18.f) : 0.f;
        expv_l[tid] = ex;
        if (tid < ansz) alpha_raw[((size_t)(t*NB + ab))*NR + an0 + tid] = ex;
        float s = ex;
        s += __shfl_xor(s, 16); s += __shfl_xor(s, 8); s += __shfl_xor(s, 4);
        s += __shfl_xor(s, 2);  s += __shfl_xor(s, 1);
        if (tid == 0) atomicAdd(&S_buf[t*NB + ab], s);
      }
      __syncthreads();
      {
        float cp = 0.f;
        const _Float16* ip = imgf_h + ((size_t)(ab*NR + an0))*DE + tid;
        for (int nl = 0; nl < ansz; nl++)
          cp += expv_l[nl] * (float)ip[(size_t)nl*DE];
        atomicAdd(&ctx_acc[((size_t)(t*NB + ab))*DE + tid], cp);
      }
    }
    gbar(bar, g, ++bc);
    // ================= P2: ctx-GEMV + finalize gates + LSTM pointwise =================
    if (tid < 32) S_l[tid] = 1.f / S_buf[t*NB + tid];
    __syncthreads();
    #pragma unroll 1
    for (int half = 0; half < 2; half++) {
      int bo = half*16;
      for (int i = tid; i < 8192; i += 512) {
        int bl = i >> 9, dI = i & 511;
        float cv = ctx_acc[((size_t)(t*NB + bo + bl))*DE + dI] * S_l[bo + bl];
        ctx_l[bl*520 + dI] = (_Float16)cv;
      }
      __syncthreads();
      {
        int bl = tid >> 5, rr = (tid >> 2) & 7, kh = tid & 3;
        const half2_t* wr = (const half2_t*)(wctx_l + rr*520);
        const half2_t* cc = (const half2_t*)(ctx_l + bl*520);
        float a = 0.f;
        #pragma unroll 8
        for (int i = 0; i < 64; i++) {
          int k2 = kh + 4*i;
          a = fdot2f(wr[k2], cc[k2], a);
        }
        a += __shfl_down(a, 2); a += __shfl_down(a, 1);
        if (kh == 0) {
          int b = bo + bl;
          int typ = rr >> 1, dl = rr & 1;
          float x = Xg[((size_t)(t*NB + b))*NG + typ*DD + d0 + dl];
          gl[b*8 + rr] = a + acc_h_l[b*8 + rr] + x;
        }
      }
      __syncthreads();
    }
    if (tid < 64) {
      int b = tid >> 1, dl = tid & 1;
      float ig = gl[b*8 + 0 + dl];
      float fg = gl[b*8 + 2 + dl];
      float gg = gl[b*8 + 4 + dl];
      float og = gl[b*8 + 6 + dl];
      float cn = fast_sig(fg)*c_reg + fast_sig(ig)*fast_tanh(gg);
      float hn = fast_sig(og)*fast_tanh(cn);
      c_reg = cn;
      float hn1 = __shfl_down(hn, 1);
      if (dl == 0) {
        U32H2 p;
        p.h[0] = (_Float16)hn;
        p.h[1] = (_Float16)hn1;
        st_au(&h_glob[b*256 + g], p.u);
        Hu[((size_t)(t*NB + b))*256 + g] = p.u;
      }
    }
    gbar(bar, g, ++bc);
  }
}

// ======================= FC GEMM (m-fastest swizzle) + alpha normalize =======================
__global__ void __launch_bounds__(256) fc_k(const _Float16* __restrict__ H,
    const _Float16* __restrict__ Wfc_h, const float* __restrict__ bfc,
    float* __restrict__ out, const float* __restrict__ alpha_raw,
    const float* __restrict__ S_buf) {
  int id = blockIdx.x;
  if (id < 4000) {
    int bm = id & 15, bn = id >> 4;   // m fastest: concurrent wgs share a small Wfc window
    gemm_tile<2>(H, 512, Wfc_h, 512, out, NV, bfc, 512, bn, bm);
  } else {
    int w = id - 4000;
    float* aout = out + (size_t)NB*NT*NV;
    int base = (w*256 + (int)threadIdx.x)*16;
    for (int j = 0; j < 16; j++) {
      int idx = base + j;
      int t = idx / 6272, r = idx - t*6272;
      int b = r / 196, n = r - b*196;
      float a = alpha_raw[idx] / S_buf[t*NB + b];
      aout[((size_t)b*NT + t)*NR + n] = a;
    }
  }
}

extern "C" void kernel_launch(void* const* d_in, const int* in_sizes, int n_in,
                              void* d_out, int out_size, void* d_ws, size_t ws_size,
                              hipStream_t stream) {
  const float* imgf  = (const float*)d_in[0];
  const int*   cap   = (const int*)d_in[1];
  const float* emb   = (const float*)d_in[2];
  const float* Wh0   = (const float*)d_in[3];
  const float* bh0   = (const float*)d_in[4];
  const float* Wc0   = (const float*)d_in[5];
  const float* bc0   = (const float*)d_in[6];
  const float* Wenc  = (const float*)d_in[7];
  const float* Wdec  = (const float*)d_in[8];
  const float* v_att = (const float*)d_in[9];
  const float* W_ih  = (const float*)d_in[10];
  const float* b_ih  = (const float*)d_in[11];
  const float* W_hh  = (const float*)d_in[12];
  const float* b_hh  = (const float*)d_in[13];
  const float* Wfc   = (const float*)d_in[14];
  const float* bfc   = (const float*)d_in[15];
  float* out = (float*)d_out;
  (void)in_sizes; (void)n_in; (void)out_size; (void)ws_size;

  char* ws = (char*)d_ws;
  size_t off = 0;
  auto alloc = [&](size_t bytes) -> void* {
    void* p = ws + off;
    off += (bytes + 255) & ~(size_t)255;
    return p;
  };
  _Float16* Wenc_h  = (_Float16*)alloc((size_t)512*512*2);
  _Float16* Wdec_h  = (_Float16*)alloc((size_t)512*512*2);
  _Float16* Wih_h   = (_Float16*)alloc((size_t)2048*1024*2);
  _Float16* Whh_h   = (_Float16*)alloc((size_t)2048*512*2);
  _Float16* Wfc_h   = (_Float16*)alloc((size_t)32000*512*2);
  _Float16* imgf_h  = (_Float16*)alloc((size_t)32*196*512*2);
  _Float16* fproj_h = (_Float16*)alloc((size_t)32*196*512*2);
  _Float16* X_h     = (_Float16*)alloc((size_t)2048*512*2);
  float*    Xg      = (float*)alloc((size_t)2048*2048*4);
  float*    bsum    = (float*)alloc((size_t)2048*4);
  float*    c0g     = (float*)alloc((size_t)32*512*4);
  unsigned* h_glob  = (unsigned*)alloc((size_t)32*256*4);
  float*    hW_glob = (float*)alloc((size_t)32*512*4);
  unsigned* Hu      = (unsigned*)alloc((size_t)2048*256*4);
  float*    alpha_raw = (float*)alloc((size_t)64*32*196*4);
  // contiguous zero region: bar(2560 B) + S_buf(8 KB) + ctx_acc(4 MB)
  unsigned* bar     = (unsigned*)alloc((size_t)640*4);
  float*    S_buf   = (float*)alloc((size_t)64*32*4);
  float*    ctx_acc = (float*)alloc((size_t)64*32*512*4);

  prep_k<<<dim3(N_PREP), dim3(256), 0, stream>>>(
      imgf, cap, emb, Wh0, bh0, Wc0, bc0, Wenc, Wdec, W_ih, b_ih, W_hh, b_hh, Wfc,
      Wenc_h, Wdec_h, Wih_h, Whh_h, Wfc_h, imgf_h, X_h, bsum, c0g, h_glob,
      (float4_t*)bar);
  g2_k<<<dim3(452), dim3(256), 0, stream>>>(imgf_h, Wenc_h, fproj_h, X_h, Wih_h, Xg, bsum);
  rec_k<<<dim3(NWG), dim3(512), 0, stream>>>(
      Wdec_h, Wih_h, Whh_h, fproj_h, imgf_h, v_att, Xg, c0g,
      h_glob, hW_glob, ctx_acc, S_buf, alpha_raw, Hu, bar);
  fc_k<<<dim3(4098), dim3(256), 0, stream>>>((const _Float16*)Hu, Wfc_h, bfc, out, alpha_raw, S_buf);
}